// Round 2
// baseline (104.930 us; speedup 1.0000x reference)
//
#include <hip/hip_runtime.h>

// AdaptivePatcher: B=32 sequences of S=16384 int32 tokens (values 0..7).
// MIN_PS=1, MAX_PS=8, LOOKAHEAD=4, THRESH=1.2 bits, PAD=0.
//
// Key parallelization facts (derived from the reference scan):
//  - hi[p] := entropy(window of up to 4 tokens at p) >= 1.2  <=>  distinct>=3
//    (n=4: {2,1,1}->1.5, {2,2}->1.0; n=3: {1,1,1}->1.585, {2,1}->0.918; n<=2 -> false)
//  - next start from i is min(next_hi[i+1], i+8, S)
//  - every hi position is a patch start; within a gap of non-hi positions after
//    anchor (last hi strictly before j, or 0 if none) starts are at anchor+8k:
//      is_start[j] = (j==0) || hi[j] || ((j - anchor(j)) % 8 == 0)
//  - size at start j = min(first d in [1,8) with hi[j+d], else 8, S-j)

#define S_LEN 16384
#define BATCH 32
#define NTHREADS 1024
#define EPT (S_LEN / NTHREADS) // 16 elements per thread
#define MAX_PS 8

__global__ __launch_bounds__(NTHREADS)
void patch_kernel(const int* __restrict__ tokens,
                  int* __restrict__ patches,  // [B, S_LEN, 8]
                  int* __restrict__ offsets,  // [B, S_LEN]
                  int* __restrict__ nout)     // [B]
{
    const int b = blockIdx.x;
    const int t = threadIdx.x;
    const int base = t * EPT;
    const int* __restrict__ seq = tokens + (size_t)b * S_LEN;
    int* __restrict__ pat = patches + (size_t)b * S_LEN * MAX_PS;
    int* __restrict__ off = offsets + (size_t)b * S_LEN;

    __shared__ unsigned char hi_s[S_LEN];
    __shared__ unsigned char flag_s[S_LEN];
    __shared__ int sc[NTHREADS];

    // ---- Phase 1: hi[] for own chunk ----
    int tk[EPT + 3];
#pragma unroll
    for (int i = 0; i < EPT + 3; ++i) {
        int j = base + i;
        tk[i] = (j < S_LEN) ? seq[j] : 0;
    }
    int chunk_hi_max = -1;
#pragma unroll
    for (int k = 0; k < EPT; ++k) {
        int j = base + k;
        int nv = min(4, S_LEN - j);
        unsigned mask = 0;
#pragma unroll
        for (int i = 0; i < 4; ++i) {
            if (i < nv) mask |= 1u << (tk[k + i] & 31);
        }
        int h = (__popc(mask) >= 3) ? 1 : 0;
        hi_s[j] = (unsigned char)h;
        if (h) chunk_hi_max = j;
    }

    // ---- Scan A: inclusive prefix-max of per-chunk last-hi index ----
    sc[t] = chunk_hi_max;
    __syncthreads();
    for (int d = 1; d < NTHREADS; d <<= 1) {
        int v = sc[t];
        int u = (t >= d) ? sc[t - d] : -1;
        __syncthreads();
        sc[t] = max(v, u);
        __syncthreads();
    }
    const int P_t = (t > 0) ? sc[t - 1] : -1; // last hi position before my chunk

    // ---- Phase 2: start flags + per-thread count ----
    int run = P_t;
    int cnt = 0;
#pragma unroll
    for (int k = 0; k < EPT; ++k) {
        int j = base + k;
        int a = (run < 0) ? 0 : run;           // anchor: last hi < j, else 0
        int h = hi_s[j];
        int is = (j == 0) || h || (((j - a) & 7) == 0);
        flag_s[j] = (unsigned char)is;
        cnt += is;
        if (h) run = j;
    }

    // ---- Scan B: exclusive prefix-sum of counts (ranks) ----
    __syncthreads(); // everyone done reading sc from scan A
    sc[t] = cnt;
    __syncthreads();
    for (int d = 1; d < NTHREADS; d <<= 1) {
        int v = sc[t];
        int u = (t >= d) ? sc[t - d] : 0;
        __syncthreads();
        sc[t] = v + u;
        __syncthreads();
    }
    int r = (t > 0) ? sc[t - 1] : 0;
    const int ntot = sc[NTHREADS - 1];

    // ---- Phase 3: emit starts (hi_s fully visible since pre-scan-A barrier) ----
#pragma unroll
    for (int k = 0; k < EPT; ++k) {
        int j = base + k;
        if (flag_s[j]) {
            int size = 8;
#pragma unroll
            for (int d = 1; d <= 7; ++d) {
                if (j + d < S_LEN && hi_s[j + d]) { size = d; break; }
            }
            size = min(size, S_LEN - j);
            off[r] = j;
            int vals[8];
#pragma unroll
            for (int q = 0; q < 8; ++q) vals[q] = (q < size) ? seq[j + q] : 0;
            int4* dst = (int4*)(pat + (size_t)r * MAX_PS);
            dst[0] = make_int4(vals[0], vals[1], vals[2], vals[3]);
            dst[1] = make_int4(vals[4], vals[5], vals[6], vals[7]);
            ++r;
        }
    }

    // ---- Phase 4: tail fill (d_out is poisoned; every element must be written) ----
    const int4 z = make_int4(0, 0, 0, 0);
    for (int r2 = ntot + t; r2 < S_LEN; r2 += NTHREADS) {
        off[r2] = -1;
        int4* dst = (int4*)(pat + (size_t)r2 * MAX_PS);
        dst[0] = z;
        dst[1] = z;
    }
    if (t == 0) nout[b] = ntot;
}

__global__ void cu_kernel(const int* __restrict__ nin, int* __restrict__ cu)
{
    if (threadIdx.x == 0) {
        int acc = 0;
        cu[0] = 0;
        for (int b = 0; b < BATCH; ++b) {
            acc += nin[b];
            cu[b + 1] = acc;
        }
    }
}

extern "C" void kernel_launch(void* const* d_in, const int* in_sizes, int n_in,
                              void* d_out, int out_size, void* d_ws, size_t ws_size,
                              hipStream_t stream)
{
    const int* tokens = (const int*)d_in[0];
    int* out = (int*)d_out;
    // Output layout (all int32, concatenated in return order):
    //   patches   [32, 16384, 8]  -> 4,194,304
    //   offsets   [32, 16384]     ->   524,288
    //   n         [32]            ->        32
    //   cu_seqlens[33]            ->        33
    int* patches = out;
    int* offsets = patches + (size_t)BATCH * S_LEN * MAX_PS;
    int* nout    = offsets + (size_t)BATCH * S_LEN;
    int* cu      = nout + BATCH;

    patch_kernel<<<dim3(BATCH), dim3(NTHREADS), 0, stream>>>(tokens, patches, offsets, nout);
    cu_kernel<<<dim3(1), dim3(64), 0, stream>>>(nout, cu);
}

// Round 3
// 72.798 us; speedup vs baseline: 1.4414x; 1.4414x over previous
//
#include <hip/hip_runtime.h>

// AdaptivePatcher: B=32 sequences of S=16384 int32 tokens (values 0..7).
// MIN_PS=1, MAX_PS=8, LOOKAHEAD=4, THRESH=1.2 bits, PAD=0.
//
// Math (verified in round 2, passed absmax=0):
//  - hi[p] := entropy(window of up to 4 tokens at p) >= 1.2  <=>  distinct>=3
//  - is_start[j] = (j==0) || hi[j] || ((j - anchor(j)) % 8 == 0),
//    anchor(j) = last hi strictly before j, else 0
//  - size at start j = min(first d in [1,8) with hi[j+d], else 8, S-j)
//
// Round-3 restructure: 3-kernel pipeline at grid=256 (one block/CU) instead of
// one 32-block kernel. Cross-chunk state is only per-chunk lastHi (prefix-max)
// and per-chunk start count (prefix-sum); with 8 chunks/seq each block reads
// the <=7 predecessor scalars directly — no long scans, no spin-waits.

#define S_LEN 16384
#define BATCH 32
#define NCH 8                  // chunks per sequence
#define CHUNK 2048             // S_LEN / NCH
#define NTH 256                // threads per block
#define PPT 8                  // positions per thread = CHUNK / NTH
#define WORDS_PER_SEQ 512      // S_LEN / 32
#define WORDS_PER_CHUNK 64     // CHUNK / 32
#define MAX_PS 8

// ---------------- K1: hi bits (packed) + per-chunk last-hi ----------------
__global__ __launch_bounds__(NTH)
void k1_hi(const int* __restrict__ tokens,
           unsigned* __restrict__ hiBits,   // [B, 512] packed bits
           int* __restrict__ lastHi)        // [B*8] last hi pos in chunk, -1 none
{
    const int blk = blockIdx.x;
    const int b = blk >> 3, c = blk & 7;
    const int t = threadIdx.x;
    const int* __restrict__ seq = tokens + (size_t)b * S_LEN;
    const int p = c * CHUNK + t * PPT;

    int v[12];
    int4 a4 = *(const int4*)(seq + p);
    int4 b4 = *(const int4*)(seq + p + 4);
    int4 c4 = make_int4(0, 0, 0, 0);
    if (p + 8 < S_LEN) c4 = *(const int4*)(seq + p + 8);
    v[0]=a4.x; v[1]=a4.y; v[2]=a4.z; v[3]=a4.w;
    v[4]=b4.x; v[5]=b4.y; v[6]=b4.z; v[7]=b4.w;
    v[8]=c4.x; v[9]=c4.y; v[10]=c4.z; v[11]=c4.w;

    unsigned byte = 0;
    int llh = -1;
#pragma unroll
    for (int k = 0; k < PPT; ++k) {
        int j = p + k;
        int nv = min(4, S_LEN - j);
        unsigned m = 0;
#pragma unroll
        for (int i = 0; i < 4; ++i) if (i < nv) m |= 1u << (v[k + i] & 31);
        int h = (__popc(m) >= 3) ? 1 : 0;
        byte |= (unsigned)h << k;
        if (h) llh = j;
    }

    __shared__ unsigned char bs[NTH];
    __shared__ int wmax[NTH / 64];
    bs[t] = (unsigned char)byte;
    int m = llh;
#pragma unroll
    for (int d = 32; d >= 1; d >>= 1) m = max(m, __shfl_down(m, d));
    if ((t & 63) == 0) wmax[t >> 6] = m;
    __syncthreads();
    if (t < WORDS_PER_CHUNK) {
        unsigned w = (unsigned)bs[4*t] | ((unsigned)bs[4*t+1] << 8) |
                     ((unsigned)bs[4*t+2] << 16) | ((unsigned)bs[4*t+3] << 24);
        hiBits[b * WORDS_PER_SEQ + c * WORDS_PER_CHUNK + t] = w;
    }
    if (t == 0)
        lastHi[blk] = max(max(wmax[0], wmax[1]), max(wmax[2], wmax[3]));
}

// ---------------- K2: per-chunk start counts ----------------
__global__ __launch_bounds__(NTH)
void k2_cnt(const unsigned* __restrict__ hiBits,
            const int* __restrict__ lastHi,
            int* __restrict__ cnt)          // [B*8]
{
    const int blk = blockIdx.x;
    const int b = blk >> 3, c = blk & 7;
    const int t = threadIdx.x;
    __shared__ unsigned hw[WORDS_PER_CHUNK];
    __shared__ int anch_s;
    __shared__ int part[NTH / 64];
    __shared__ int psum[NTH / 64];

    if (t < WORDS_PER_CHUNK) hw[t] = hiBits[b*WORDS_PER_SEQ + c*WORDS_PER_CHUNK + t];
    if (t == 0) {
        int a = -1;
        for (int i = 0; i < c; ++i) a = max(a, lastHi[b*NCH + i]);
        anch_s = a;
    }
    __syncthreads();

    const int p = c * CHUNK + t * PPT;
    unsigned hb = (hw[t >> 2] >> ((t & 3) * 8)) & 0xffu;
    int llh = -1;
#pragma unroll
    for (int k = 0; k < PPT; ++k) if ((hb >> k) & 1u) llh = p + k;

    // block exclusive prefix-max of llh (wave shfl scan + 4 partials)
    const int lane = t & 63, wv = t >> 6;
    int incl = llh;
#pragma unroll
    for (int d = 1; d < 64; d <<= 1) {
        int u = __shfl_up(incl, d);
        if (lane >= d) incl = max(incl, u);
    }
    if (lane == 63) part[wv] = incl;
    __syncthreads();
    int excl = __shfl_up(incl, 1);
    if (lane == 0) excl = -1;
    int run = anch_s;
    for (int w = 0; w < wv; ++w) run = max(run, part[w]);
    run = max(run, excl);

    int cl = 0;
#pragma unroll
    for (int k = 0; k < PPT; ++k) {
        int j = p + k;
        int h = (hb >> k) & 1u;
        int a = (run < 0) ? 0 : run;
        int is = (j == 0) | h | (((j - a) & 7) == 0);
        cl += is;
        if (h) run = j;
    }
    int s = cl;
#pragma unroll
    for (int d = 32; d >= 1; d >>= 1) s += __shfl_down(s, d);
    if (lane == 0) psum[wv] = s;
    __syncthreads();
    if (t == 0) cnt[blk] = psum[0] + psum[1] + psum[2] + psum[3];
}

// ---------------- K3: ranks + emit + tail fill ----------------
__global__ __launch_bounds__(NTH)
void k3_emit(const int* __restrict__ tokens,
             const unsigned* __restrict__ hiBits,
             const int* __restrict__ lastHi,
             const int* __restrict__ cnt,
             int* __restrict__ patches,     // [B, S, 8]
             int* __restrict__ offsets,     // [B, S]
             int* __restrict__ nout)        // [B]
{
    const int blk = blockIdx.x;
    const int b = blk >> 3, c = blk & 7;
    const int t = threadIdx.x;
    const int* __restrict__ seq = tokens + (size_t)b * S_LEN;
    int* __restrict__ pat = patches + (size_t)b * S_LEN * MAX_PS;
    int* __restrict__ off = offsets + (size_t)b * S_LEN;

    __shared__ unsigned hw[WORDS_PER_CHUNK + 2];
    __shared__ int anch_s, base_s, ntot_s;
    __shared__ int part[NTH / 64];
    __shared__ int spart[NTH / 64];

    if (t < WORDS_PER_CHUNK + 2) {
        int widx = c * WORDS_PER_CHUNK + t;
        hw[t] = (widx < WORDS_PER_SEQ) ? hiBits[b*WORDS_PER_SEQ + widx] : 0u;
    }
    if (t == 0) {
        int a = -1, rb = 0, nt = 0;
        for (int i = 0; i < NCH; ++i) {
            int cv = cnt[b*NCH + i];
            nt += cv;
            if (i < c) { rb += cv; a = max(a, lastHi[b*NCH + i]); }
        }
        anch_s = a; base_s = rb; ntot_s = nt;
    }
    __syncthreads();

    const int p = c * CHUNK + t * PPT;
    unsigned hb = (hw[t >> 2] >> ((t & 3) * 8)) & 0xffu;
    int llh = -1;
#pragma unroll
    for (int k = 0; k < PPT; ++k) if ((hb >> k) & 1u) llh = p + k;

    const int lane = t & 63, wv = t >> 6;
    // exclusive prefix-max -> incoming run
    int incl = llh;
#pragma unroll
    for (int d = 1; d < 64; d <<= 1) {
        int u = __shfl_up(incl, d);
        if (lane >= d) incl = max(incl, u);
    }
    if (lane == 63) part[wv] = incl;
    __syncthreads();
    int excl = __shfl_up(incl, 1);
    if (lane == 0) excl = -1;
    int run = anch_s;
    for (int w = 0; w < wv; ++w) run = max(run, part[w]);
    run = max(run, excl);

    // flags + local count
    unsigned fb = 0;
    int cl = 0;
#pragma unroll
    for (int k = 0; k < PPT; ++k) {
        int j = p + k;
        int h = (hb >> k) & 1u;
        int a = (run < 0) ? 0 : run;
        int is = (j == 0) | h | (((j - a) & 7) == 0);
        fb |= (unsigned)is << k;
        cl += is;
        if (h) run = j;
    }

    // block exclusive prefix-sum of counts -> rank
    int sincl = cl;
#pragma unroll
    for (int d = 1; d < 64; d <<= 1) {
        int u = __shfl_up(sincl, d);
        if (lane >= d) sincl += u;
    }
    if (lane == 63) spart[wv] = sincl;
    __syncthreads();
    int sexcl = __shfl_up(sincl, 1);
    if (lane == 0) sexcl = 0;
    int r = base_s + sexcl;
    for (int w = 0; w < wv; ++w) r += spart[w];

    // emit
#pragma unroll
    for (int k = 0; k < PPT; ++k) {
        if ((fb >> k) & 1u) {
            int j = p + k;
            int lb = t * PPT + k;        // local bit index within chunk
            int size = 8;
#pragma unroll
            for (int d = 1; d <= 7; ++d) {
                int bb = lb + d;
                if ((hw[bb >> 5] >> (bb & 31)) & 1u) { size = d; break; }
            }
            size = min(size, S_LEN - j);
            int vals[8];
#pragma unroll
            for (int q = 0; q < 8; ++q) vals[q] = (q < size) ? seq[j + q] : 0;
            off[r] = j;
            int4* dst = (int4*)(pat + (size_t)r * MAX_PS);
            dst[0] = make_int4(vals[0], vals[1], vals[2], vals[3]);
            dst[1] = make_int4(vals[4], vals[5], vals[6], vals[7]);
            ++r;
        }
    }

    // tail fill: rows [ntot, S), strided over this seq's 8 blocks x 256 threads
    const int ntot = ntot_s;
    const int4 z = make_int4(0, 0, 0, 0);
    for (int r2 = ntot + c * NTH + t; r2 < S_LEN; r2 += CHUNK) {
        off[r2] = -1;
        int4* dst = (int4*)(pat + (size_t)r2 * MAX_PS);
        dst[0] = z;
        dst[1] = z;
    }
    if (c == 0 && t == 0) nout[b] = ntot;
}

// ---------------- cu_seqlens: one-wave shfl scan ----------------
__global__ void cu_kernel(const int* __restrict__ nin, int* __restrict__ cu)
{
    int t = threadIdx.x;
    int v = (t < BATCH) ? nin[t] : 0;
#pragma unroll
    for (int d = 1; d < 32; d <<= 1) {
        int u = __shfl_up(v, d);
        if (t >= d) v += u;
    }
    if (t < BATCH) cu[t + 1] = v;
    if (t == 0) cu[0] = 0;
}

extern "C" void kernel_launch(void* const* d_in, const int* in_sizes, int n_in,
                              void* d_out, int out_size, void* d_ws, size_t ws_size,
                              hipStream_t stream)
{
    const int* tokens = (const int*)d_in[0];
    int* out = (int*)d_out;
    // Output layout (all int32, concatenated in return order):
    //   patches   [32, 16384, 8]  -> 4,194,304
    //   offsets   [32, 16384]     ->   524,288
    //   n         [32]            ->        32
    //   cu_seqlens[33]            ->        33
    int* patches = out;
    int* offsets = patches + (size_t)BATCH * S_LEN * MAX_PS;
    int* nout    = offsets + (size_t)BATCH * S_LEN;
    int* cu      = nout + BATCH;

    // workspace: hiBits 64KB, lastHi 1KB, cnt 1KB (all written before read)
    unsigned* hiBits = (unsigned*)d_ws;
    int* lastHi = (int*)(hiBits + (size_t)BATCH * WORDS_PER_SEQ);
    int* cnt    = lastHi + BATCH * NCH;

    k1_hi  <<<dim3(BATCH * NCH), dim3(NTH), 0, stream>>>(tokens, hiBits, lastHi);
    k2_cnt <<<dim3(BATCH * NCH), dim3(NTH), 0, stream>>>(hiBits, lastHi, cnt);
    k3_emit<<<dim3(BATCH * NCH), dim3(NTH), 0, stream>>>(tokens, hiBits, lastHi, cnt,
                                                         patches, offsets, nout);
    cu_kernel<<<dim3(1), dim3(64), 0, stream>>>(nout, cu);
}